// Round 7
// baseline (255.808 us; speedup 1.0000x reference)
//
#include <hip/hip_runtime.h>
#include <hip/hip_bf16.h>

typedef __attribute__((ext_vector_type(4))) float f32x4;
typedef __attribute__((ext_vector_type(8))) short s16x8;

static __device__ __forceinline__ short f2bf(float x) {
  __hip_bfloat16 h = __float2bfloat16(x);
  return *reinterpret_cast<short*>(&h);
}

// Workgroup barrier that waits ONLY on LDS (lgkmcnt), not vmcnt.
// __syncthreads() makes the compiler emit s_waitcnt vmcnt(0) before s_barrier,
// which drains our in-flight register prefetch loads every site (m97 stall).
// Cross-wave hazards here are LDS-only; vmem register consumers get their own
// dataflow s_waitcnt from the compiler. "memory" clobber pins ordering.
static __device__ __forceinline__ void barrier_lds() {
  asm volatile("s_waitcnt lgkmcnt(0)\n\ts_barrier" ::: "memory");
}

// ---------------- MFMA MPS stages 1..3 with fused BatchNorm + inline Lw ----------------
// Block = patch p, 256 thr = 4 waves. Wave q owns batch rows [16q,16q+16).
// v (fp32, canonical in LDS) updated per site via bf16 MFMA correction:
//   dv[b][j] = sum_k W[b][k]*C'[k][j],  K = 5 blocks of 32:
//   blocks g=0..3: C'[32g+i][j]=cd_g[i][j], W=u_g*v[i]; block 4: csum-I, W=v[i].
// One LDS-only barrier per site; prefetch distance 3 via two ping-pong register sets.
// NOTE: Cl must be FULLY zeroed once — writeC never touches k-columns i in 20..31 of
// rows 0..19, but B-frag reads sweep all 32 k-lanes (A is 0 there; garbage*0 can be NaN).
template<int STAGE>
__global__ __launch_bounds__(256)
void k_mps(const float* __restrict__ xsrc, const float* __restrict__ ysrc,
           const float* __restrict__ cores, const float* __restrict__ alpha,
           const float* __restrict__ label, const float* __restrict__ omega,
           const float* __restrict__ gam, const float* __restrict__ bet,
           float* __restrict__ yout) {
  constexpr int S = (STAGE == 1) ? 3 : 20;
  __shared__ __align__(16) float u4[S][64][4];      // [site][b][g]
  __shared__ __align__(16) short Cl[2][32][168];    // [buf][n-row][k'], pad 168
  __shared__ __align__(16) float vls[64][36];       // [b][i], cols 20..35 zero
  __shared__ float Lw_l[400];
  __shared__ float redA[4], redB[4], stats[2];

  const int p = blockIdx.x, t = threadIdx.x;
  const int b = t & 63, q = t >> 6;
  const int m = b & 15, quad = b >> 4;
  const int bl = q * 16 + m;

  const bool two = (t < 144);                        // 400 = 256 + 144
  const float* cbase = cores + (size_t)p * S * 3200;

  // ---- issue site-0 raw core loads (in flight during all init) ----
  float p0A[8], p0B[8], p1A[8], p1B[8];
#pragma unroll
  for (int g = 0; g < 8; ++g) p0A[g] = cbase[g * 400 + t];
  if (two) {
#pragma unroll
    for (int g = 0; g < 8; ++g) p0B[g] = cbase[g * 400 + 256 + t];
  }

  // ---- Lw[o][j] = sum_k label[o][j][k]*omega[k] (L3-hot, overlapped with prefetch) ----
  for (int e = t; e < 400; e += 256) {
    int o = e / 20, j = e % 20;
    float a = 0.f;
#pragma unroll
    for (int k = 0; k < 20; ++k) a = fmaf(label[o * 400 + j * 20 + k], omega[k], a);
    Lw_l[e] = a;
  }

  // ---- zero FULL C' (both buffers); init v = alpha (cols >=20 zero) ----
  {
    int* cz = (int*)&Cl[0][0][0];                    // 2*32*168 shorts = 5376 ints
    for (int i = t; i < 5376; i += 256) cz[i] = 0;
    for (int i = t; i < 64 * 36; i += 256) {
      int col = i % 36;
      vls[i / 36][col] = (col < 20) ? alpha[col] : 0.f;
    }
  }

  // ---- gather u (faithful raw-reshape unfold permutation); u4[k][b][g=q] ----
  for (int k = 0; k < S; ++k) {
    float val;
    if (STAGE == 1) {
      int L = q * 3072 + p * 3 + k;           // [4,1024,3] flat
      int c = L >> 12, r = L & 4095;          // dims [3,32,32,2,2]
      int hh = 2 * (r >> 7) + ((r >> 1) & 1);
      int ww = 2 * ((r >> 2) & 31) + (r & 1);
      val = xsrc[(b * 3 + c) * 4096 + hh * 64 + ww];
    } else if (STAGE == 2) {
      int L = q * 5120 + p * 20 + k;          // [4,256,20] flat
      int c = L >> 10, r = L & 1023;          // dims [20,16,16,2,2]
      int f = c * 1024 + (2 * (r >> 6) + ((r >> 1) & 1)) * 32
                        + (2 * ((r >> 2) & 15) + (r & 1));
      val = ysrc[f * 64 + b];                 // b innermost -> coalesced
    } else {
      int L = q * 1280 + p * 20 + k;          // [4,64,20] flat
      int c = L >> 8, r = L & 255;            // dims [20,8,8,2,2]
      int f = c * 256 + (2 * (r >> 5) + ((r >> 1) & 1)) * 16
                       + (2 * ((r >> 2) & 7) + (r & 1));
      val = ysrc[f * 64 + b];
    }
    u4[k][b][q] = val;
  }

  // C'-entry writer: entry e=(i*20+j) from raw feature regs r[0..8)
  auto writeC = [&](int buf, int e, const float* r) {
    int i = e / 20, j = e % 20;
    Cl[buf][j][      i] = f2bf(r[0] - r[4]);
    Cl[buf][j][ 32 + i] = f2bf(r[1] - r[5]);
    Cl[buf][j][ 64 + i] = f2bf(r[2] - r[6]);
    Cl[buf][j][ 96 + i] = f2bf(r[3] - r[7]);
    float cs = r[4] + r[5] + r[6] + r[7];
    if (i == j) cs -= 1.f;
    Cl[buf][j][128 + i] = f2bf(cs);
  };
  auto loadSite = [&](int s, float (&rA)[8], float (&rB)[8]) {
    const float* cs = cbase + (size_t)s * 3200;
#pragma unroll
    for (int g = 0; g < 8; ++g) rA[g] = cs[g * 400 + t];
    if (two) {
#pragma unroll
      for (int g = 0; g < 8; ++g) rB[g] = cs[g * 400 + 256 + t];
    }
  };

  // build C'[0] from site-0 regs; then fill the pipeline: s1 -> P0, s2 -> P1
  writeC(0, t, p0A);
  if (two) writeC(0, t + 256, p0B);
  if (S > 1) loadSite(1, p0A, p0B);
  if (S > 2) loadSite(2, p1A, p1B);
  barrier_lds();

  // ---- one site step; cur/regset passed statically (no dynamic reg indexing) ----
  auto site_step = [&](int s, int cur, float (&rA)[8], float (&rB)[8]) {
    const float4 uu = *(const float4*)&u4[s][bl][0];
    const float4 va = *(const float4*)&vls[bl][quad * 8];
    const float4 vb = *(const float4*)&vls[bl][quad * 8 + 4];
    const float vv[8] = {va.x, va.y, va.z, va.w, vb.x, vb.y, vb.z, vb.w};
    const float um[5] = {uu.x, uu.y, uu.z, uu.w, 1.f};

    f32x4 acc0 = {0.f, 0.f, 0.f, 0.f};
    f32x4 acc1 = {0.f, 0.f, 0.f, 0.f};
#pragma unroll
    for (int kt = 0; kt < 5; ++kt) {
      s16x8 aF;
#pragma unroll
      for (int j2 = 0; j2 < 8; ++j2) aF[j2] = f2bf(vv[j2] * um[kt]);
      const s16x8 bF0 = *(const s16x8*)&Cl[cur][m][kt * 32 + quad * 8];
      const s16x8 bF1 = *(const s16x8*)&Cl[cur][m + 16][kt * 32 + quad * 8];
      acc0 = __builtin_amdgcn_mfma_f32_16x16x32_bf16(aF, bF0, acc0, 0, 0, 0);
      acc1 = __builtin_amdgcn_mfma_f32_16x16x32_bf16(aF, bF1, acc1, 0, 0, 0);
    }

    // stage next site's C' (regs loaded 2 sites ago); refill this regset for s+3
    if (s + 1 < S) {
      writeC(cur ^ 1, t, rA);
      if (two) writeC(cur ^ 1, t + 256, rB);
      if (s + 3 < S) loadSite(s + 3, rA, rB);
    }

    // v += dv  (intra-wave: each (b,j) owned by exactly one lane of wave q)
#pragma unroll
    for (int r = 0; r < 4; ++r) vls[q * 16 + quad * 4 + r][m] += acc0[r];
    if (m < 4) {
#pragma unroll
      for (int r = 0; r < 4; ++r) vls[q * 16 + quad * 4 + r][m + 16] += acc1[r];
    }
    barrier_lds();   // LDS-only barrier: does NOT drain the prefetch vmcnt
  };

  for (int s = 0; s < S; s += 2) {
    site_step(s, 0, p0A, p0B);
    if (s + 1 < S) site_step(s + 1, 1, p1A, p1B);
  }

  // ---- epilogue: Lw projection + fused BatchNorm (stats over 64b x 20o) ----
  float vf[20];
  {
    const float4 v0 = *(const float4*)&vls[b][0];
    const float4 v1 = *(const float4*)&vls[b][4];
    const float4 v2 = *(const float4*)&vls[b][8];
    const float4 v3 = *(const float4*)&vls[b][12];
    const float4 v4 = *(const float4*)&vls[b][16];
    vf[0]=v0.x; vf[1]=v0.y; vf[2]=v0.z; vf[3]=v0.w;
    vf[4]=v1.x; vf[5]=v1.y; vf[6]=v1.z; vf[7]=v1.w;
    vf[8]=v2.x; vf[9]=v2.y; vf[10]=v2.z; vf[11]=v2.w;
    vf[12]=v3.x; vf[13]=v3.y; vf[14]=v3.z; vf[15]=v3.w;
    vf[16]=v4.x; vf[17]=v4.y; vf[18]=v4.z; vf[19]=v4.w;
  }
  float yo[5];
  float s1 = 0.f, s2 = 0.f;
#pragma unroll
  for (int jj = 0; jj < 5; ++jj) {
    int o = q * 5 + jj;
    float a = 0.f;
#pragma unroll
    for (int j = 0; j < 20; ++j) a = fmaf(vf[j], Lw_l[o * 20 + j], a);
    yo[jj] = a; s1 += a; s2 += a * a;
  }
#pragma unroll
  for (int off = 32; off > 0; off >>= 1) {
    s1 += __shfl_down(s1, off); s2 += __shfl_down(s2, off);
  }
  if (b == 0) { redA[q] = s1; redB[q] = s2; }
  __syncthreads();
  if (t == 0) {
    float S1 = redA[0] + redA[1] + redA[2] + redA[3];
    float S2 = redB[0] + redB[1] + redB[2] + redB[3];
    float mu = S1 * (1.f / 1280.f);
    float var = S2 * (1.f / 1280.f) - mu * mu;
    if (var < 0.f) var = 0.f;
    stats[0] = mu; stats[1] = var;
  }
  __syncthreads();
  float mu = stats[0], var = stats[1];
  float scale = gam[p] / sqrtf(var + 1e-5f);
  float shift = bet[p] - mu * scale;
#pragma unroll
  for (int jj = 0; jj < 5; ++jj) {
    int o = q * 5 + jj;
    yout[(p * 20 + o) * 64 + b] = fmaf(yo[jj], scale, shift);   // coalesced over b
  }
}

// ---------------- Final MPS (S=64 sites, F=40): chunked partial matrix products ----------------
__global__ __launch_bounds__(256)
void k_f1(const float* __restrict__ y3n, const float* __restrict__ coresF,
          float* __restrict__ PP) {
  const int bid = blockIdx.x;
  const int b = bid >> 3, c = bid & 7;
  const int t = threadIdx.x;
  __shared__ float ybuf[8][20];
  __shared__ float M[400];
  __shared__ float Pb[2][400];
  if (t < 160) ybuf[t / 20][t % 20] = y3n[(c * 160 + t) * 64 + b];
  __syncthreads();
  int cur = 0;
  for (int s = 0; s < 8; ++s) {
    const float* cf = coresF + (size_t)(c * 8 + s) * 16000;  // [site][40][400]
    for (int e = t; e < 400; e += 256) {
      float m = 0.f;
#pragma unroll
      for (int g = 0; g < 20; ++g) {
        float lo = cf[g * 400 + e];          // phi_g = y_g
        float hi = cf[(g + 20) * 400 + e];   // phi_{g+20} = 1 - y_g
        m += fmaf(ybuf[s][g], lo - hi, hi);
      }
      M[e] = m;
    }
    __syncthreads();
    if (s == 0) {
      for (int e = t; e < 400; e += 256) Pb[0][e] = M[e];
    } else {
      for (int e = t; e < 400; e += 256) {
        int i = e / 20, j = e % 20;
        float a = 0.f;
#pragma unroll
        for (int k = 0; k < 20; ++k)
          a = fmaf(Pb[cur][i * 20 + k], M[k * 20 + j], a);
        Pb[cur ^ 1][e] = a;
      }
      cur ^= 1;
    }
    __syncthreads();
  }
  for (int e = t; e < 400; e += 256) PP[(size_t)bid * 400 + e] = Pb[cur][e];
}

__global__ __launch_bounds__(256)
void k_f2(const float* __restrict__ PP, const float* __restrict__ alphaF,
          const float* __restrict__ labelF, const float* __restrict__ omegaF,
          float* __restrict__ out) {
  const int b = blockIdx.x, t = threadIdx.x;
  __shared__ float Pb[2][400];
  __shared__ float M[400];
  __shared__ float va[20];
  __shared__ float LwF_l[200];
  if (t < 200) {
    int o = t / 20, j = t % 20;
    float a = 0.f;
#pragma unroll
    for (int k = 0; k < 20; ++k) a = fmaf(labelF[o * 400 + j * 20 + k], omegaF[k], a);
    LwF_l[t] = a;
  }
  for (int e = t; e < 400; e += 256) Pb[0][e] = PP[(size_t)b * 3200 + e];
  int cur = 0;
  for (int c = 1; c < 8; ++c) {
    for (int e = t; e < 400; e += 256) M[e] = PP[(size_t)b * 3200 + c * 400 + e];
    __syncthreads();
    for (int e = t; e < 400; e += 256) {
      int i = e / 20, j = e % 20;
      float a = 0.f;
#pragma unroll
      for (int k = 0; k < 20; ++k) a = fmaf(Pb[cur][i * 20 + k], M[k * 20 + j], a);
      Pb[cur ^ 1][e] = a;
    }
    cur ^= 1;
    __syncthreads();
  }
  if (t < 20) {
    float a = 0.f;
#pragma unroll
    for (int i = 0; i < 20; ++i) a = fmaf(alphaF[i], Pb[cur][i * 20 + t], a);
    va[t] = a;
  }
  __syncthreads();
  if (t < 10) {
    float a = 0.f;
#pragma unroll
    for (int j = 0; j < 20; ++j) a = fmaf(va[j], LwF_l[t * 20 + j], a);
    out[b * 10 + t] = a;
  }
}

extern "C" void kernel_launch(void* const* d_in, const int* in_sizes, int n_in,
                              void* d_out, int out_size, void* d_ws, size_t ws_size,
                              hipStream_t stream) {
  const float* x      = (const float*)d_in[0];
  const float* cores1 = (const float*)d_in[1];
  const float* label1 = (const float*)d_in[2];
  const float* alpha1 = (const float*)d_in[3];
  const float* omega1 = (const float*)d_in[4];
  const float* g1     = (const float*)d_in[5];
  const float* b1     = (const float*)d_in[6];
  const float* cores2 = (const float*)d_in[7];
  const float* label2 = (const float*)d_in[8];
  const float* alpha2 = (const float*)d_in[9];
  const float* omega2 = (const float*)d_in[10];
  const float* g2     = (const float*)d_in[11];
  const float* b2     = (const float*)d_in[12];
  const float* cores3 = (const float*)d_in[13];
  const float* label3 = (const float*)d_in[14];
  const float* alpha3 = (const float*)d_in[15];
  const float* omega3 = (const float*)d_in[16];
  const float* g3     = (const float*)d_in[17];
  const float* b3     = (const float*)d_in[18];
  const float* coresF = (const float*)d_in[19];
  const float* labelF = (const float*)d_in[20];
  const float* alphaF = (const float*)d_in[21];
  const float* omegaF = (const float*)d_in[22];

  float* ws  = (float*)d_ws;
  float* yn1 = ws;               // 20480*64
  float* yn2 = yn1 + 1310720;    // 5120*64
  float* yn3 = yn2 + 327680;     // 1280*64
  float* PP  = yn3 + 81920;      // 512*400
  float* out = (float*)d_out;

  k_mps<1><<<1024, 256, 0, stream>>>(x, nullptr, cores1, alpha1, label1, omega1, g1, b1, yn1);
  k_mps<2><<<256, 256, 0, stream>>>(nullptr, yn1, cores2, alpha2, label2, omega2, g2, b2, yn2);
  k_mps<3><<<64, 256, 0, stream>>>(nullptr, yn2, cores3, alpha3, label3, omega3, g3, b3, yn3);
  k_f1<<<512, 256, 0, stream>>>(yn3, coresF, PP);
  k_f2<<<64, 256, 0, stream>>>(PP, alphaF, labelF, omegaF, out);
}